// Round 12
// baseline (445.006 us; speedup 1.0000x reference)
//
#include <hip/hip_runtime.h>

typedef unsigned int u32;
typedef int i32x4 __attribute__((ext_vector_type(4)));
typedef float f32x4 __attribute__((ext_vector_type(4)));

#define HWP  3136      // H*W
#define NPOS 100352    // B*H*W
#define NMBLK 1568     // NPOS / 64  (m-tiles; 49 per image)

// ---- workspace layout (bytes) ----
// act_t: chunk-major packed activations: act_t[chunk(0..15)][pos][16B]
#define ACT_OFF 0ull
#define ACT_BYTES (25690112ull)
#define W8_OFF  (ACT_OFF + ACT_BYTES)           // i8 w   [3][256][256]
#define W8_BYTES (196608ull)
#define SC_OFF  (W8_OFF + W8_BYTES)             // f32 scales [3][256]
#define SC_BYTES (3072ull)
#define PS_OFF  (SC_OFF + SC_BYTES)             // f32 ps [256][NMBLK]
#define PS_BYTES (256ull * NMBLK * 4)
#define PQ_OFF  (PS_OFF + PS_BYTES)             // f32 pq [256][NMBLK]
#define PQ_BYTES (256ull * NMBLK * 4)
#define PAR_OFF (PQ_OFF + PQ_BYTES)             // f32 par [2][256]

// K0: weights -> i8 sign (+1/-1), per-out-channel scale = mean|w|.
__global__ __launch_bounds__(64) void k_pack_w(
    const float* __restrict__ w1, const float* __restrict__ w2,
    const float* __restrict__ w3, signed char* __restrict__ w8,
    float* __restrict__ scales) {
  int bid = blockIdx.x;
  int conv = bid >> 8, p = bid & 255;
  const float* w = (conv == 0) ? w1 : (conv == 1) ? w2 : w3;
  int lane = threadIdx.x;
  float asum = 0.0f;
#pragma unroll
  for (int k = 0; k < 4; ++k) {
    float v = w[p * 256 + k * 64 + lane];
    asum += fabsf(v);
    w8[(size_t)(conv * 256 + p) * 256 + k * 64 + lane] =
        (v > 0.0f) ? (signed char)1 : (signed char)-1;
  }
#pragma unroll
  for (int off = 32; off > 0; off >>= 1) asum += __shfl_down(asum, off);
  if (lane == 0) scales[conv * 256 + p] = asum * (1.0f / 256.0f);
}

// K1: act_t[chunk][pos] = sign(x + bias0) as i8 (+1 -> 0x01, -1 -> 0xFF).
__global__ __launch_bounds__(256) void k_pack_a(
    const float* __restrict__ x, const float* __restrict__ bias0,
    i32x4* __restrict__ act16) {
  int pos = blockIdx.x * 256 + threadIdx.x;
  int b = pos / HWP;
  int hw = pos - b * HWP;
  const float* xp = x + (size_t)b * 256 * HWP + hw;
#pragma unroll 2
  for (int c16 = 0; c16 < 16; ++c16) {
    i32x4 vv;
#pragma unroll
    for (int q = 0; q < 4; ++q) {
      u32 bb = 0;
#pragma unroll
      for (int cc = 0; cc < 4; ++cc) {
        int c = c16 * 16 + q * 4 + cc;
        float v = xp[(size_t)c * HWP] + bias0[c];
        bb |= (u32)((v > 0.0f) ? 0x01u : 0xFFu) << (cc * 8);
      }
      vv[q] = (int)bb;
    }
    act16[(size_t)c16 * NPOS + pos] = vv;
  }
}

// Neighbor positions for the 9 shift variants (circular roll per image).
__device__ __forceinline__ void neighbor_pos(int row, int base, int (&p9)[9]) {
  int h = row / 56;
  int w = row - h * 56;
  p9[0] = base + row;
  int hm1 = (h == 0) ? 55 : h - 1, hp1 = (h == 55) ? 0 : h + 1;
  int wm1 = (w == 0) ? 55 : w - 1, wp1 = (w == 55) ? 0 : w + 1;
  int hm3 = (h < 3) ? h + 53 : h - 3, hp3 = (h >= 53) ? h - 53 : h + 3;
  int wm3 = (w < 3) ? w + 53 : w - 3, wp3 = (w >= 53) ? w - 53 : w + 3;
  p9[1] = base + hm1 * 56 + w;  p9[2] = base + hp1 * 56 + w;
  p9[3] = base + h * 56 + wm1;  p9[4] = base + h * 56 + wp1;
  p9[5] = base + hm3 * 56 + w;  p9[6] = base + hp3 * 56 + w;
  p9[7] = base + h * 56 + wm3;  p9[8] = base + h * 56 + wp3;
}

// Issue the 12 A-fragment loads (3 conv variants x 4 ksteps) for one msub.
__device__ __forceinline__ void lda(const i32x4* __restrict__ act16, int base,
                                    int rowin, int l4, i32x4 (&A)[12]) {
  int p9[9];
  neighbor_pos(rowin, base, p9);
#pragma unroll
  for (int ks = 0; ks < 4; ++ks) {
    const i32x4* cb = act16 + (size_t)(ks * 4 + l4) * NPOS;
    A[ks] = cb[p9[0]];
    A[4 + ks] = cb[p9[1 + ks]];
    A[8 + ks] = cb[p9[5 + ks]];
  }
}

// 24 MFMA on one msub's A buffer against TWO B-tiles -> two scaled f32x4.
__device__ __forceinline__ void domfma2(const i32x4 (&A)[12],
                                        const i32x4 (&bf0)[12],
                                        const i32x4 (&bf1)[12],
                                        const float (&sc)[6], f32x4& s0,
                                        f32x4& s1) {
  i32x4 a0[3] = {{0,0,0,0},{0,0,0,0},{0,0,0,0}};
  i32x4 a1[3] = {{0,0,0,0},{0,0,0,0},{0,0,0,0}};
  __builtin_amdgcn_s_setprio(1);
#pragma unroll
  for (int ks = 0; ks < 4; ++ks) {
#pragma unroll
    for (int conv = 0; conv < 3; ++conv) {
      a0[conv] = __builtin_amdgcn_mfma_i32_16x16x64_i8(
          A[conv * 4 + ks], bf0[conv * 4 + ks], a0[conv], 0, 0, 0);
      a1[conv] = __builtin_amdgcn_mfma_i32_16x16x64_i8(
          A[conv * 4 + ks], bf1[conv * 4 + ks], a1[conv], 0, 0, 0);
    }
  }
  __builtin_amdgcn_s_setprio(0);
#pragma unroll
  for (int r = 0; r < 4; ++r) {
    s0[r] = sc[0] * (float)a0[0][r] + sc[1] * (float)a0[1][r] +
            sc[2] * (float)a0[2][r];
    s1[r] = sc[3] * (float)a1[0][r] + sc[4] * (float)a1[1][r] +
            sc[5] * (float)a1[2][r];
  }
}

// Bijective XCD swizzle for m-tiles (1568 = 8 * 196).
__device__ __forceinline__ int swz_m(int bid) {
  return (bid & 7) * 196 + (bid >> 3);
}

// Load B fragments + scales for one 16-ch tile.
__device__ __forceinline__ void ldb(const signed char* __restrict__ w8,
                                    const float* __restrict__ scales, int ch,
                                    int l4, i32x4 (&bf)[12], float* sc) {
#pragma unroll
  for (int conv = 0; conv < 3; ++conv) {
#pragma unroll
    for (int ks = 0; ks < 4; ++ks)
      bf[conv * 4 + ks] = *(const i32x4*)(w8 + (size_t)(conv * 256 + ch) * 256 +
                                          ks * 64 + l4 * 16);
    sc[conv] = scales[conv * 256 + ch];
  }
}

// K2: GEMM + BN-statistics partials. Block = 1 wave (64 thr), 32 channels
// (2 B-tiles), 1 m-tile (4 msubs), double-buffered A prefetch, no barriers.
// *** A/B arm 1: NO waves_per_eu pin — compiler picks VGPR/occupancy. ***
// Compare VGPR_Count/dur against k_out2 (pinned) in the same bench.
__global__ __launch_bounds__(64) void k_stats2(
    const i32x4* __restrict__ act16, const signed char* __restrict__ w8,
    const float* __restrict__ scales, float* __restrict__ ps,
    float* __restrict__ pq) {
  const int lane = threadIdx.x & 63;
  const int l15 = lane & 15, l4 = lane >> 4;
  const int m = swz_m(blockIdx.x);
  const int ch0 = blockIdx.y * 32 + l15, ch1 = ch0 + 16;

  i32x4 bf0[12], bf1[12];
  float sc[6];
  ldb(w8, scales, ch0, l4, bf0, sc);
  ldb(w8, scales, ch1, l4, bf1, sc + 3);

  int bimg = m / 49;
  int hw0 = (m - bimg * 49) * 64;
  int base = bimg * HWP;

  i32x4 bufA[12], bufB[12];
  lda(act16, base, hw0 + l15, l4, bufA);
  float ss0 = 0.0f, sq0 = 0.0f, ss1 = 0.0f, sq1 = 0.0f;
#pragma unroll
  for (int msub = 0; msub < 4; ++msub) {
    i32x4(&cur)[12] = (msub & 1) ? bufB : bufA;
    i32x4(&nxt)[12] = (msub & 1) ? bufA : bufB;
    if (msub < 3) lda(act16, base, hw0 + (msub + 1) * 16 + l15, l4, nxt);
    f32x4 s0, s1;
    domfma2(cur, bf0, bf1, sc, s0, s1);
#pragma unroll
    for (int r = 0; r < 4; ++r) {
      ss0 += s0[r]; sq0 = fmaf(s0[r], s0[r], sq0);
      ss1 += s1[r]; sq1 = fmaf(s1[r], s1[r], sq1);
    }
  }
  ss0 += __shfl_xor(ss0, 16); sq0 += __shfl_xor(sq0, 16);
  ss0 += __shfl_xor(ss0, 32); sq0 += __shfl_xor(sq0, 32);
  ss1 += __shfl_xor(ss1, 16); sq1 += __shfl_xor(sq1, 16);
  ss1 += __shfl_xor(ss1, 32); sq1 += __shfl_xor(sq1, 32);
  if (l4 == 0) {
    ps[(size_t)ch0 * NMBLK + m] = ss0;
    pq[(size_t)ch0 * NMBLK + m] = sq0;
    ps[(size_t)ch1 * NMBLK + m] = ss1;
    pq[(size_t)ch1 * NMBLK + m] = sq1;
  }
}

// K3: reduce partials (f64) -> folded BN affine.
__global__ __launch_bounds__(256) void k_bn(
    const float* __restrict__ ps, const float* __restrict__ pq,
    const float* __restrict__ gamma, const float* __restrict__ beta,
    const float* __restrict__ bias1, float* __restrict__ par) {
  int ch = blockIdx.x;
  int tid = threadIdx.x;
  double as = 0.0, aq = 0.0;
  for (int i = tid; i < NMBLK; i += 256) {
    as += (double)ps[(size_t)ch * NMBLK + i];
    aq += (double)pq[(size_t)ch * NMBLK + i];
  }
  __shared__ double sd0[256], sd1[256];
  sd0[tid] = as; sd1[tid] = aq;
  __syncthreads();
  for (int s = 128; s > 0; s >>= 1) {
    if (tid < s) { sd0[tid] += sd0[tid + s]; sd1[tid] += sd1[tid + s]; }
    __syncthreads();
  }
  if (tid == 0) {
    double mean = sd0[0] * (1.0 / NPOS);
    double var = sd1[0] * (1.0 / NPOS) - mean * mean;
    float mm = (float)((double)gamma[ch] / sqrt(var + 1e-5));
    par[ch] = mm;
    par[256 + ch] = beta[ch] + bias1[ch] - (float)mean * mm;
  }
}

// K4: GEMM + BN affine + residual + PReLU + bias2 -> out (NCHW f32).
// *** A/B arm 2: waves_per_eu(2,2) pins regalloc to the 256-VGPR budget so
// the persistent B-fragments + A double-buffer (192 VGPRs) stay resident
// (round-6 lesson: launch_bounds alone -> compiler chose 120 VGPRs and
// spilled the software pipeline). ***
__global__ __launch_bounds__(64)
__attribute__((amdgpu_waves_per_eu(2, 2))) void k_out2(
    const i32x4* __restrict__ act16, const signed char* __restrict__ w8,
    const float* __restrict__ scales, const float* __restrict__ par,
    const float* __restrict__ alpha, const float* __restrict__ bias2,
    const float* __restrict__ x, float* __restrict__ out) {
  const int lane = threadIdx.x & 63;
  const int l15 = lane & 15, l4 = lane >> 4;
  const int m = swz_m(blockIdx.x);
  const int ch0 = blockIdx.y * 32 + l15, ch1 = ch0 + 16;

  i32x4 bf0[12], bf1[12];
  float sc[6];
  ldb(w8, scales, ch0, l4, bf0, sc);
  ldb(w8, scales, ch1, l4, bf1, sc + 3);
  float mul0 = par[ch0], add0 = par[256 + ch0], al0 = alpha[ch0],
        b20 = bias2[ch0];
  float mul1 = par[ch1], add1 = par[256 + ch1], al1 = alpha[ch1],
        b21 = bias2[ch1];

  int bimg = m / 49;
  int hw0 = (m - bimg * 49) * 64;
  int base = bimg * HWP;
  size_t xb0 = ((size_t)bimg * 256 + ch0) * HWP + hw0 + l4 * 4;
  size_t xb1 = ((size_t)bimg * 256 + ch1) * HWP + hw0 + l4 * 4;

  i32x4 bufA[12], bufB[12];
  lda(act16, base, hw0 + l15, l4, bufA);
#pragma unroll
  for (int msub = 0; msub < 4; ++msub) {
    i32x4(&cur)[12] = (msub & 1) ? bufB : bufA;
    i32x4(&nxt)[12] = (msub & 1) ? bufA : bufB;
    if (msub < 3) lda(act16, base, hw0 + (msub + 1) * 16 + l15, l4, nxt);
    f32x4 xv0 = *(const f32x4*)(x + xb0 + msub * 16);
    f32x4 xv1 = *(const f32x4*)(x + xb1 + msub * 16);
    f32x4 s0, s1;
    domfma2(cur, bf0, bf1, sc, s0, s1);
    f32x4 o0, o1;
#pragma unroll
    for (int r = 0; r < 4; ++r) {
      float t0 = fmaf(s0[r], mul0, add0) + xv0[r];
      t0 = (t0 >= 0.0f) ? t0 : al0 * t0;
      o0[r] = t0 + b20;
      float t1 = fmaf(s1[r], mul1, add1) + xv1[r];
      t1 = (t1 >= 0.0f) ? t1 : al1 * t1;
      o1[r] = t1 + b21;
    }
    *(f32x4*)(out + xb0 + msub * 16) = o0;
    *(f32x4*)(out + xb1 + msub * 16) = o1;
  }
}

extern "C" void kernel_launch(void* const* d_in, const int* in_sizes, int n_in,
                              void* d_out, int out_size, void* d_ws,
                              size_t ws_size, hipStream_t stream) {
  const float* x     = (const float*)d_in[0];
  const float* bias0 = (const float*)d_in[1];
  const float* w1    = (const float*)d_in[2];
  const float* w2    = (const float*)d_in[3];
  const float* w3    = (const float*)d_in[4];
  const float* gamma = (const float*)d_in[5];
  const float* beta  = (const float*)d_in[6];
  const float* bias1 = (const float*)d_in[7];
  const float* alpha = (const float*)d_in[8];
  const float* bias2 = (const float*)d_in[9];
  float* out = (float*)d_out;

  char* ws = (char*)d_ws;
  i32x4* act16     = (i32x4*)(ws + ACT_OFF);
  signed char* w8  = (signed char*)(ws + W8_OFF);
  float* scales    = (float*)(ws + SC_OFF);
  float* ps        = (float*)(ws + PS_OFF);
  float* pq        = (float*)(ws + PQ_OFF);
  float* par       = (float*)(ws + PAR_OFF);

  hipLaunchKernelGGL(k_pack_w, dim3(768), dim3(64), 0, stream, w1, w2, w3, w8,
                     scales);
  hipLaunchKernelGGL(k_pack_a, dim3(392), dim3(256), 0, stream, x, bias0,
                     act16);
  hipLaunchKernelGGL(k_stats2, dim3(NMBLK, 8), dim3(64), 0, stream, act16,
                     w8, scales, ps, pq);
  hipLaunchKernelGGL(k_bn, dim3(256), dim3(256), 0, stream, ps, pq, gamma,
                     beta, bias1, par);
  hipLaunchKernelGGL(k_out2, dim3(NMBLK, 8), dim3(64), 0, stream, act16, w8,
                     scales, par, alpha, bias2, x, out);
}